// Round 1
// baseline (632.445 us; speedup 1.0000x reference)
//
#include <hip/hip_runtime.h>
#include <math.h>

#define PI_HALF 1.57079632679489662f

// ---------------- 4-qubit state helpers (compile-time masks -> registers) ----
// wire w (0..3) maps to amplitude-index bit (3-w), i.e. mask = 8 >> w.

__device__ __forceinline__ void init_state(float sr[16], float si[16]) {
#pragma unroll
    for (int i = 0; i < 16; ++i) { sr[i] = 0.f; si[i] = 0.f; }
    sr[0] = 1.f;
}

template<int M>
__device__ __forceinline__ void ry_g(float sr[16], float si[16], float c, float s) {
#pragma unroll
    for (int i = 0; i < 16; ++i) {
        if (i & M) continue;
        const int j = i | M;
        float ar = sr[i], ai = si[i], br = sr[j], bi = si[j];
        sr[i] = c * ar - s * br;  si[i] = c * ai - s * bi;
        sr[j] = s * ar + c * br;  si[j] = s * ai + c * bi;
    }
}

template<int M>
__device__ __forceinline__ void had_g(float sr[16], float si[16]) {
    const float r = 0.70710678118654752f;
#pragma unroll
    for (int i = 0; i < 16; ++i) {
        if (i & M) continue;
        const int j = i | M;
        float ar = sr[i], ai = si[i], br = sr[j], bi = si[j];
        sr[i] = (ar + br) * r;  si[i] = (ai + bi) * r;
        sr[j] = (ar - br) * r;  si[j] = (ai - bi) * r;
    }
}

template<int MC, int MT>
__device__ __forceinline__ void cnot_g(float sr[16], float si[16]) {
#pragma unroll
    for (int i = 0; i < 16; ++i) {
        if (!(i & MC) || (i & MT)) continue;
        const int j = i | MT;
        float tr = sr[i], ti = si[i];
        sr[i] = sr[j]; si[i] = si[j];
        sr[j] = tr;    si[j] = ti;
    }
}

template<int MC, int MT>
__device__ __forceinline__ void cry_g(float sr[16], float si[16], float c, float s) {
#pragma unroll
    for (int i = 0; i < 16; ++i) {
        if (!(i & MC) || (i & MT)) continue;
        const int j = i | MT;
        float ar = sr[i], ai = si[i], br = sr[j], bi = si[j];
        sr[i] = c * ar - s * br;  si[i] = c * ai - s * bi;
        sr[j] = s * ar + c * br;  si[j] = s * ai + c * bi;
    }
}

// PennyLane Rot = RZ(omega) @ RY(theta) @ RZ(phi)
// U00 = e^{-i(phi+omega)/2} c ; U01 = -e^{+i(phi-omega)/2} s
// U10 = e^{-i(phi-omega)/2} s ; U11 = e^{+i(phi+omega)/2} c
template<int M>
__device__ __forceinline__ void rot_g(float sr[16], float si[16],
                                      float phi, float theta, float omega) {
    float st, ct; sincosf(0.5f * theta, &st, &ct);
    float sp, cp; sincosf(0.5f * (phi + omega), &sp, &cp);
    float sm, cm; sincosf(0.5f * (phi - omega), &sm, &cm);
    float u00r =  ct * cp, u00i = -ct * sp;
    float u01r = -st * cm, u01i = -st * sm;
    float u10r =  st * cm, u10i = -st * sm;
    float u11r =  ct * cp, u11i =  ct * sp;
#pragma unroll
    for (int i = 0; i < 16; ++i) {
        if (i & M) continue;
        const int j = i | M;
        float ar = sr[i], ai = si[i], br = sr[j], bi = si[j];
        sr[i] = u00r * ar - u00i * ai + u01r * br - u01i * bi;
        si[i] = u00r * ai + u00i * ar + u01r * bi + u01i * br;
        sr[j] = u10r * ar - u10i * ai + u11r * br - u11i * bi;
        si[j] = u10r * ai + u10i * ar + u11r * bi + u11i * br;
    }
}

__device__ __forceinline__ void zexp_g(const float sr[16], const float si[16], float z[4]) {
    float p[16];
#pragma unroll
    for (int i = 0; i < 16; ++i) p[i] = sr[i] * sr[i] + si[i] * si[i];
    z[0] = z[1] = z[2] = z[3] = 0.f;
#pragma unroll
    for (int i = 0; i < 16; ++i) {
        z[0] += (i & 8) ? -p[i] : p[i];
        z[1] += (i & 4) ? -p[i] : p[i];
        z[2] += (i & 2) ? -p[i] : p[i];
        z[3] += (i & 1) ? -p[i] : p[i];
    }
}

// ---------------- kernels ---------------------------------------------------

// h = relu(x @ W_in^T + b_in), x:[N,64] W:[128,64] -> h:[N,128]
__global__ void k_in(const float* __restrict__ x, const float* __restrict__ W,
                     const float* __restrict__ b, float* __restrict__ h, int N) {
    __shared__ float xs[16 * 64];
    const int base = blockIdx.x * 16;
    const int tid = threadIdx.x;  // 128
    for (int idx = tid; idx < 16 * 64; idx += 128) {
        int n = base + (idx >> 6);
        xs[idx] = (n < N) ? x[(size_t)n * 64 + (idx & 63)] : 0.f;
    }
    __syncthreads();
    float acc[16];
#pragma unroll
    for (int n = 0; n < 16; ++n) acc[n] = 0.f;
    const float4* wr4 = (const float4*)(W + tid * 64);
    for (int c4 = 0; c4 < 16; ++c4) {
        float4 w = wr4[c4];
#pragma unroll
        for (int n = 0; n < 16; ++n) {
            float4 hv = *(const float4*)&xs[n * 64 + c4 * 4];
            acc[n] += w.x * hv.x + w.y * hv.y + w.z * hv.z + w.w * hv.w;
        }
    }
    const float bb = b[tid];
#pragma unroll
    for (int n = 0; n < 16; ++n) {
        int node = base + n;
        if (node < N) h[(size_t)node * 128 + tid] = fmaxf(acc[n] + bb, 0.f);
    }
}

// entangle circuit per node: angles = tanh(h[:,0:4])*pi/2, ent params ep[2][4][3]
__global__ void k_ent(const float* __restrict__ h, const float* __restrict__ ep,
                      float* __restrict__ xq, int N) {
    int n = blockIdx.x * blockDim.x + threadIdx.x;
    if (n >= N) return;
    float a[4];
#pragma unroll
    for (int i = 0; i < 4; ++i) a[i] = tanhf(h[(size_t)n * 128 + i]) * PI_HALF;
    float sr[16], si[16];
    init_state(sr, si);
    { float s, c; sincosf(0.5f * a[0], &s, &c); ry_g<8>(sr, si, c, s); }
    { float s, c; sincosf(0.5f * a[1], &s, &c); ry_g<4>(sr, si, c, s); }
    { float s, c; sincosf(0.5f * a[2], &s, &c); ry_g<2>(sr, si, c, s); }
    { float s, c; sincosf(0.5f * a[3], &s, &c); ry_g<1>(sr, si, c, s); }
#pragma unroll
    for (int l = 0; l < 2; ++l) {
        cnot_g<8, 4>(sr, si); cnot_g<4, 2>(sr, si); cnot_g<2, 1>(sr, si);
        const float* P = ep + l * 12;
        rot_g<8>(sr, si, P[0], P[1], P[2]);
        rot_g<4>(sr, si, P[3], P[4], P[5]);
        rot_g<2>(sr, si, P[6], P[7], P[8]);
        rot_g<1>(sr, si, P[9], P[10], P[11]);
        cnot_g<8, 1>(sr, si);  // CNOT(0, 3)
    }
    float z[4]; zexp_g(sr, si, z);
#pragma unroll
    for (int i = 0; i < 4; ++i) xq[(size_t)n * 4 + i] = z[i];
}

// per-node: x_comb = lin_W@h + lin_b + qproj_W@xq + qproj_b; q/k = tanh(attX_W@h+b)*pi/2
__global__ void k_lin(const float* __restrict__ h, const float* __restrict__ xq,
                      const float* __restrict__ linW, const float* __restrict__ linb,
                      const float* __restrict__ qpW, const float* __restrict__ qpb,
                      const float* __restrict__ aqW, const float* __restrict__ aqb,
                      const float* __restrict__ akW, const float* __restrict__ akb,
                      float* __restrict__ xcomb, float* __restrict__ qbuf,
                      float* __restrict__ kbuf, int N) {
    __shared__ float hs[16 * 128];
    __shared__ float xqs[16 * 4];
    const int base = blockIdx.x * 16;
    const int tid = threadIdx.x;  // 128
    for (int idx = tid; idx < 16 * 128; idx += 128) {
        int n = base + (idx >> 7);
        hs[idx] = (n < N) ? h[(size_t)n * 128 + (idx & 127)] : 0.f;
    }
    if (tid < 64) {
        int n = base + (tid >> 2);
        xqs[tid] = (n < N) ? xq[(size_t)n * 4 + (tid & 3)] : 0.f;
    }
    __syncthreads();
    float acc[16];
#pragma unroll
    for (int n = 0; n < 16; ++n) acc[n] = 0.f;
    const float4* wr4 = (const float4*)(linW + tid * 128);
    for (int c4 = 0; c4 < 32; ++c4) {
        float4 w = wr4[c4];
#pragma unroll
        for (int n = 0; n < 16; ++n) {
            float4 hv = *(const float4*)&hs[n * 128 + c4 * 4];
            acc[n] += w.x * hv.x + w.y * hv.y + w.z * hv.z + w.w * hv.w;
        }
    }
    const float bb = linb[tid] + qpb[tid];
    const float qw0 = qpW[tid * 4 + 0], qw1 = qpW[tid * 4 + 1];
    const float qw2 = qpW[tid * 4 + 2], qw3 = qpW[tid * 4 + 3];
#pragma unroll
    for (int n = 0; n < 16; ++n) {
        int node = base + n;
        if (node < N) {
            xcomb[(size_t)node * 128 + tid] = acc[n] + bb
                + qw0 * xqs[n * 4 + 0] + qw1 * xqs[n * 4 + 1]
                + qw2 * xqs[n * 4 + 2] + qw3 * xqs[n * 4 + 3];
        }
    }
    // q/k: 128 threads = 16 nodes x (4 q + 4 k)
    const int nl = tid >> 3;
    const int which = tid & 7;
    const int qi = which & 3;
    const float4* Wp4 = (const float4*)(((which < 4) ? aqW : akW) + qi * 128);
    float dot = (which < 4) ? aqb[qi] : akb[qi];
    for (int c4 = 0; c4 < 32; ++c4) {
        float4 w = Wp4[c4];
        float4 hv = *(const float4*)&hs[nl * 128 + c4 * 4];
        dot += w.x * hv.x + w.y * hv.y + w.z * hv.z + w.w * hv.w;
    }
    int node = base + nl;
    if (node < N) {
        float val = tanhf(dot) * PI_HALF;
        if (which < 4) qbuf[(size_t)node * 4 + qi] = val;
        else           kbuf[(size_t)node * 4 + qi] = val;
    }
}

// attention circuit per edge -> score
__global__ void k_att(const float* __restrict__ qb, const float* __restrict__ kb,
                      const int* __restrict__ ei, const float* __restrict__ P,
                      float* __restrict__ scores, int E, int EP) {
    int e = blockIdx.x * blockDim.x + threadIdx.x;
    if (e >= EP) return;
    int s_, d_;
    if (e < E) { s_ = ei[e]; d_ = ei[E + e]; } else { s_ = d_ = e - E; }
    float4 q = *(const float4*)&qb[(size_t)s_ * 4];
    float4 k = *(const float4*)&kb[(size_t)d_ * 4];
    float sr[16], si[16];
    init_state(sr, si);
    { float s, c; sincosf(0.5f * q.x, &s, &c); ry_g<8>(sr, si, c, s); }
    { float s, c; sincosf(0.5f * q.y, &s, &c); ry_g<4>(sr, si, c, s); }
    { float s, c; sincosf(0.5f * q.z, &s, &c); ry_g<2>(sr, si, c, s); }
    { float s, c; sincosf(0.5f * q.w, &s, &c); ry_g<1>(sr, si, c, s); }
    had_g<8>(sr, si); had_g<4>(sr, si); had_g<2>(sr, si); had_g<1>(sr, si);
    { float s, c; sincosf(0.5f * k.x, &s, &c); cry_g<8, 4>(sr, si, c, s); }
    { float s, c; sincosf(0.5f * k.y, &s, &c); cry_g<4, 2>(sr, si, c, s); }
    { float s, c; sincosf(0.5f * k.z, &s, &c); cry_g<2, 1>(sr, si, c, s); }
    { float s, c; sincosf(0.5f * k.w, &s, &c); cry_g<1, 8>(sr, si, c, s); }
    rot_g<8>(sr, si, P[0], P[1], P[2]);
    rot_g<4>(sr, si, P[3], P[4], P[5]);
    rot_g<2>(sr, si, P[6], P[7], P[8]);
    rot_g<1>(sr, si, P[9], P[10], P[11]);
    float z[4]; zexp_g(sr, si, z);
    scores[e] = 0.25f * (z[0] + z[1] + z[2] + z[3]);
}

// sum of exp(scores); scores in [-1,1] so no max-subtraction needed
__global__ void k_sumexp(const float* __restrict__ scores, float* __restrict__ sum, int EP) {
    __shared__ float red[256];
    float acc = 0.f;
    for (int e = blockIdx.x * blockDim.x + threadIdx.x; e < EP; e += gridDim.x * blockDim.x)
        acc += expf(scores[e]);
    red[threadIdx.x] = acc;
    __syncthreads();
    for (int s = 128; s > 0; s >>= 1) {
        if ((int)threadIdx.x < s) red[threadIdx.x] += red[threadIdx.x + s];
        __syncthreads();
    }
    if (threadIdx.x == 0) atomicAdd(sum, red[0]);
}

// hnew[dst,:] += (exp(score)/S) * xcomb[src,:]
__global__ void k_scatter(const float* __restrict__ xcomb, const float* __restrict__ scores,
                          const float* __restrict__ sum, const int* __restrict__ ei,
                          float* __restrict__ hnew, int E, int EP) {
    int eb = blockIdx.x * 2 + (threadIdx.x >> 7);
    int j = threadIdx.x & 127;
    if (eb >= EP) return;
    int s_, d_;
    if (eb < E) { s_ = ei[eb]; d_ = ei[E + eb]; } else { s_ = d_ = eb - E; }
    float w = expf(scores[eb]) / sum[0];
    float v = w * xcomb[(size_t)s_ * 128 + j];
    unsafeAtomicAdd(&hnew[(size_t)d_ * 128 + j], v);  // native global_atomic_add_f32
}

__global__ void k_relu(const float* __restrict__ a, float* __restrict__ b, int n) {
    int i = blockIdx.x * blockDim.x + threadIdx.x;
    if (i < n) b[i] = fmaxf(a[i], 0.f);
}

// M = out_W @ path_out_W  (32x4);  v = out_W @ path_out_b + out_b  (32)
__global__ void k_fusemat(const float* __restrict__ outW, const float* __restrict__ outb,
                          const float* __restrict__ poW, const float* __restrict__ pob,
                          float* __restrict__ M, float* __restrict__ v) {
    int t = threadIdx.x;
    if (t < 128) {
        int o = t >> 2, i = t & 3;
        float acc = 0.f;
        for (int j = 0; j < 128; ++j) acc += outW[o * 128 + j] * poW[j * 4 + i];
        M[t] = acc;
    } else if (t < 160) {
        int o = t - 128;
        float acc = outb[o];
        for (int j = 0; j < 128; ++j) acc += outW[o * 128 + j] * pob[j];
        v[o] = acc;
    }
}

// per node: pq = tanh(path_in_W@h + b)*pi/2 ; path circuit ; out = M@z + v
__global__ void k_path(const float* __restrict__ h, const float* __restrict__ piW,
                       const float* __restrict__ pib, const float* __restrict__ pp,
                       const float* __restrict__ M, const float* __restrict__ v,
                       float* __restrict__ out, int N) {
    __shared__ float wS[512];
    __shared__ float MS[128];
    __shared__ float vS[32];
    __shared__ float ppS[36];
    __shared__ float pibS[4];
    const int tid = threadIdx.x;  // 64
    for (int i = tid; i < 512; i += 64) wS[i] = piW[i];
    for (int i = tid; i < 128; i += 64) MS[i] = M[i];
    if (tid < 32) vS[tid] = v[tid];
    if (tid < 36) ppS[tid] = pp[tid];
    if (tid < 4) pibS[tid] = pib[tid];
    __syncthreads();
    int n = blockIdx.x * 64 + tid;
    if (n >= N) return;
    float a[4] = { pibS[0], pibS[1], pibS[2], pibS[3] };
    const float4* hr4 = (const float4*)(h + (size_t)n * 128);
    for (int c4 = 0; c4 < 32; ++c4) {
        float4 hv = hr4[c4];
#pragma unroll
        for (int i = 0; i < 4; ++i) {
            float4 w = *(const float4*)&wS[i * 128 + c4 * 4];
            a[i] += w.x * hv.x + w.y * hv.y + w.z * hv.z + w.w * hv.w;
        }
    }
#pragma unroll
    for (int i = 0; i < 4; ++i) a[i] = tanhf(a[i]) * PI_HALF;
    float sr[16], si[16];
    init_state(sr, si);
    had_g<8>(sr, si); had_g<4>(sr, si); had_g<2>(sr, si); had_g<1>(sr, si);
    { float s, c; sincosf(0.5f * a[0], &s, &c); ry_g<8>(sr, si, c, s); }
    { float s, c; sincosf(0.5f * a[1], &s, &c); ry_g<4>(sr, si, c, s); }
    { float s, c; sincosf(0.5f * a[2], &s, &c); ry_g<2>(sr, si, c, s); }
    { float s, c; sincosf(0.5f * a[3], &s, &c); ry_g<1>(sr, si, c, s); }
#pragma unroll
    for (int l = 0; l < 3; ++l) {
        const float* P = ppS + l * 12;
        rot_g<8>(sr, si, P[0], P[1], P[2]);
        rot_g<4>(sr, si, P[3], P[4], P[5]);
        rot_g<2>(sr, si, P[6], P[7], P[8]);
        rot_g<1>(sr, si, P[9], P[10], P[11]);
        cnot_g<8, 4>(sr, si); cnot_g<4, 2>(sr, si); cnot_g<2, 1>(sr, si);
    }
    float z[4]; zexp_g(sr, si, z);
    float* op = out + (size_t)n * 32;
#pragma unroll
    for (int o = 0; o < 32; ++o) {
        op[o] = vS[o] + MS[o * 4 + 0] * z[0] + MS[o * 4 + 1] * z[1]
                      + MS[o * 4 + 2] * z[2] + MS[o * 4 + 3] * z[3];
    }
}

// ---------------- launch ----------------------------------------------------

extern "C" void kernel_launch(void* const* d_in, const int* in_sizes, int n_in,
                              void* d_out, int out_size, void* d_ws, size_t ws_size,
                              hipStream_t stream) {
    const float* x     = (const float*)d_in[0];
    const float* W_in  = (const float*)d_in[1];
    const float* b_in  = (const float*)d_in[2];
    const float* linW  = (const float*)d_in[3];
    const float* linb  = (const float*)d_in[4];
    const float* qpW   = (const float*)d_in[5];
    const float* qpb   = (const float*)d_in[6];
    const float* entp  = (const float*)d_in[7];
    const float* aqW   = (const float*)d_in[8];
    const float* aqb   = (const float*)d_in[9];
    const float* akW   = (const float*)d_in[10];
    const float* akb   = (const float*)d_in[11];
    const float* attqp = (const float*)d_in[12];
    const float* pparm = (const float*)d_in[13];
    const float* piW   = (const float*)d_in[14];
    const float* pib   = (const float*)d_in[15];
    const float* poW   = (const float*)d_in[16];
    const float* pob   = (const float*)d_in[17];
    const float* outW  = (const float*)d_in[18];
    const float* outb  = (const float*)d_in[19];
    const int*   ei    = (const int*)d_in[20];

    const int N  = in_sizes[0] / 64;   // 20000
    const int E  = in_sizes[20] / 2;   // 300000
    const int EP = E + N;              // self-loops appended

    float* ws     = (float*)d_ws;
    float* h      = ws;
    float* hnew   = h     + (size_t)N * 128;
    float* xcomb  = hnew  + (size_t)N * 128;
    float* xq     = xcomb + (size_t)N * 128;
    float* qbuf   = xq    + (size_t)N * 4;
    float* kbuf   = qbuf  + (size_t)N * 4;
    float* scores = kbuf  + (size_t)N * 4;
    float* sumexp = scores + EP;
    float* Mm     = sumexp + 1;
    float* vv     = Mm + 128;

    const int nb16 = (N + 15) / 16;

    k_in<<<nb16, 128, 0, stream>>>(x, W_in, b_in, h, N);

    for (int l = 0; l < 2; ++l) {
        k_ent<<<(N + 255) / 256, 256, 0, stream>>>(h, entp + l * 24, xq, N);
        k_lin<<<nb16, 128, 0, stream>>>(h, xq,
            linW + (size_t)l * 128 * 128, linb + l * 128,
            qpW + (size_t)l * 128 * 4, qpb + l * 128,
            aqW + (size_t)l * 4 * 128, aqb + l * 4,
            akW + (size_t)l * 4 * 128, akb + l * 4,
            xcomb, qbuf, kbuf, N);
        k_att<<<(EP + 255) / 256, 256, 0, stream>>>(qbuf, kbuf, ei, attqp + l * 12,
                                                    scores, E, EP);
        hipMemsetAsync(sumexp, 0, sizeof(float), stream);
        k_sumexp<<<512, 256, 0, stream>>>(scores, sumexp, EP);
        hipMemsetAsync(hnew, 0, (size_t)N * 128 * sizeof(float), stream);
        k_scatter<<<(EP + 1) / 2, 256, 0, stream>>>(xcomb, scores, sumexp, ei, hnew, E, EP);
        k_relu<<<(N * 128 + 255) / 256, 256, 0, stream>>>(hnew, h, N * 128);
    }

    k_fusemat<<<1, 192, 0, stream>>>(outW, outb, poW, pob, Mm, vv);
    k_path<<<(N + 63) / 64, 64, 0, stream>>>(h, piW, pib, pparm, Mm, vv,
                                             (float*)d_out, N);
}

// Round 2
// 425.043 us; speedup vs baseline: 1.4880x; 1.4880x over previous
//
#include <hip/hip_runtime.h>
#include <math.h>

#define PI_HALF 1.57079632679489662f

// ---------------- 4-qubit state helpers (compile-time masks -> registers) ----
// wire w (0..3) maps to amplitude-index bit (3-w), i.e. mask = 8 >> w.

__device__ __forceinline__ void init_state(float sr[16], float si[16]) {
#pragma unroll
    for (int i = 0; i < 16; ++i) { sr[i] = 0.f; si[i] = 0.f; }
    sr[0] = 1.f;
}

template<int M>
__device__ __forceinline__ void ry_g(float sr[16], float si[16], float c, float s) {
#pragma unroll
    for (int i = 0; i < 16; ++i) {
        if (i & M) continue;
        const int j = i | M;
        float ar = sr[i], ai = si[i], br = sr[j], bi = si[j];
        sr[i] = c * ar - s * br;  si[i] = c * ai - s * bi;
        sr[j] = s * ar + c * br;  si[j] = s * ai + c * bi;
    }
}

template<int M>
__device__ __forceinline__ void had_g(float sr[16], float si[16]) {
    const float r = 0.70710678118654752f;
#pragma unroll
    for (int i = 0; i < 16; ++i) {
        if (i & M) continue;
        const int j = i | M;
        float ar = sr[i], ai = si[i], br = sr[j], bi = si[j];
        sr[i] = (ar + br) * r;  si[i] = (ai + bi) * r;
        sr[j] = (ar - br) * r;  si[j] = (ai - bi) * r;
    }
}

template<int MC, int MT>
__device__ __forceinline__ void cnot_g(float sr[16], float si[16]) {
#pragma unroll
    for (int i = 0; i < 16; ++i) {
        if (!(i & MC) || (i & MT)) continue;
        const int j = i | MT;
        float tr = sr[i], ti = si[i];
        sr[i] = sr[j]; si[i] = si[j];
        sr[j] = tr;    si[j] = ti;
    }
}

template<int MC, int MT>
__device__ __forceinline__ void cry_g(float sr[16], float si[16], float c, float s) {
#pragma unroll
    for (int i = 0; i < 16; ++i) {
        if (!(i & MC) || (i & MT)) continue;
        const int j = i | MT;
        float ar = sr[i], ai = si[i], br = sr[j], bi = si[j];
        sr[i] = c * ar - s * br;  si[i] = c * ai - s * bi;
        sr[j] = s * ar + c * br;  si[j] = s * ai + c * bi;
    }
}

// PennyLane Rot = RZ(omega) @ RY(theta) @ RZ(phi)
template<int M>
__device__ __forceinline__ void rot_g(float sr[16], float si[16],
                                      float phi, float theta, float omega) {
    float st, ct; sincosf(0.5f * theta, &st, &ct);
    float sp, cp; sincosf(0.5f * (phi + omega), &sp, &cp);
    float sm, cm; sincosf(0.5f * (phi - omega), &sm, &cm);
    float u00r =  ct * cp, u00i = -ct * sp;
    float u01r = -st * cm, u01i = -st * sm;
    float u10r =  st * cm, u10i = -st * sm;
    float u11r =  ct * cp, u11i =  ct * sp;
#pragma unroll
    for (int i = 0; i < 16; ++i) {
        if (i & M) continue;
        const int j = i | M;
        float ar = sr[i], ai = si[i], br = sr[j], bi = si[j];
        sr[i] = u00r * ar - u00i * ai + u01r * br - u01i * bi;
        si[i] = u00r * ai + u00i * ar + u01r * bi + u01i * br;
        sr[j] = u10r * ar - u10i * ai + u11r * br - u11i * bi;
        si[j] = u10r * ai + u10i * ar + u11r * bi + u11i * br;
    }
}

__device__ __forceinline__ void zexp_g(const float sr[16], const float si[16], float z[4]) {
    float p[16];
#pragma unroll
    for (int i = 0; i < 16; ++i) p[i] = sr[i] * sr[i] + si[i] * si[i];
    z[0] = z[1] = z[2] = z[3] = 0.f;
#pragma unroll
    for (int i = 0; i < 16; ++i) {
        z[0] += (i & 8) ? -p[i] : p[i];
        z[1] += (i & 4) ? -p[i] : p[i];
        z[2] += (i & 2) ? -p[i] : p[i];
        z[3] += (i & 1) ? -p[i] : p[i];
    }
}

// ---------------- kernels ---------------------------------------------------

// h = relu(x @ W_in^T + b_in), x:[N,64] W:[128,64] -> h:[N,128]
__global__ void k_in(const float* __restrict__ x, const float* __restrict__ W,
                     const float* __restrict__ b, float* __restrict__ h, int N) {
    __shared__ float xs[16 * 64];
    const int base = blockIdx.x * 16;
    const int tid = threadIdx.x;  // 128
    for (int idx = tid; idx < 16 * 64; idx += 128) {
        int n = base + (idx >> 6);
        xs[idx] = (n < N) ? x[(size_t)n * 64 + (idx & 63)] : 0.f;
    }
    __syncthreads();
    float acc[16];
#pragma unroll
    for (int n = 0; n < 16; ++n) acc[n] = 0.f;
    const float4* wr4 = (const float4*)(W + tid * 64);
    for (int c4 = 0; c4 < 16; ++c4) {
        float4 w = wr4[c4];
#pragma unroll
        for (int n = 0; n < 16; ++n) {
            float4 hv = *(const float4*)&xs[n * 64 + c4 * 4];
            acc[n] += w.x * hv.x + w.y * hv.y + w.z * hv.z + w.w * hv.w;
        }
    }
    const float bb = b[tid];
#pragma unroll
    for (int n = 0; n < 16; ++n) {
        int node = base + n;
        if (node < N) h[(size_t)node * 128 + tid] = fmaxf(acc[n] + bb, 0.f);
    }
}

// entangle circuit per node
__global__ void k_ent(const float* __restrict__ h, const float* __restrict__ ep,
                      float* __restrict__ xq, int N) {
    int n = blockIdx.x * blockDim.x + threadIdx.x;
    if (n >= N) return;
    float4 hv = *(const float4*)&h[(size_t)n * 128];
    float a[4] = { tanhf(hv.x) * PI_HALF, tanhf(hv.y) * PI_HALF,
                   tanhf(hv.z) * PI_HALF, tanhf(hv.w) * PI_HALF };
    float sr[16], si[16];
    init_state(sr, si);
    { float s, c; sincosf(0.5f * a[0], &s, &c); ry_g<8>(sr, si, c, s); }
    { float s, c; sincosf(0.5f * a[1], &s, &c); ry_g<4>(sr, si, c, s); }
    { float s, c; sincosf(0.5f * a[2], &s, &c); ry_g<2>(sr, si, c, s); }
    { float s, c; sincosf(0.5f * a[3], &s, &c); ry_g<1>(sr, si, c, s); }
#pragma unroll
    for (int l = 0; l < 2; ++l) {
        cnot_g<8, 4>(sr, si); cnot_g<4, 2>(sr, si); cnot_g<2, 1>(sr, si);
        const float* P = ep + l * 12;
        rot_g<8>(sr, si, P[0], P[1], P[2]);
        rot_g<4>(sr, si, P[3], P[4], P[5]);
        rot_g<2>(sr, si, P[6], P[7], P[8]);
        rot_g<1>(sr, si, P[9], P[10], P[11]);
        cnot_g<8, 1>(sr, si);  // CNOT(0, 3)
    }
    float z[4]; zexp_g(sr, si, z);
    *(float4*)&xq[(size_t)n * 4] = make_float4(z[0], z[1], z[2], z[3]);
}

// per-node: x_comb, q, k
__global__ void k_lin(const float* __restrict__ h, const float* __restrict__ xq,
                      const float* __restrict__ linW, const float* __restrict__ linb,
                      const float* __restrict__ qpW, const float* __restrict__ qpb,
                      const float* __restrict__ aqW, const float* __restrict__ aqb,
                      const float* __restrict__ akW, const float* __restrict__ akb,
                      float* __restrict__ xcomb, float* __restrict__ qbuf,
                      float* __restrict__ kbuf, int N) {
    __shared__ float hs[16 * 128];
    __shared__ float xqs[16 * 4];
    const int base = blockIdx.x * 16;
    const int tid = threadIdx.x;  // 128
    for (int idx = tid; idx < 16 * 128; idx += 128) {
        int n = base + (idx >> 7);
        hs[idx] = (n < N) ? h[(size_t)n * 128 + (idx & 127)] : 0.f;
    }
    if (tid < 64) {
        int n = base + (tid >> 2);
        xqs[tid] = (n < N) ? xq[(size_t)n * 4 + (tid & 3)] : 0.f;
    }
    __syncthreads();
    float acc[16];
#pragma unroll
    for (int n = 0; n < 16; ++n) acc[n] = 0.f;
    const float4* wr4 = (const float4*)(linW + tid * 128);
    for (int c4 = 0; c4 < 32; ++c4) {
        float4 w = wr4[c4];
#pragma unroll
        for (int n = 0; n < 16; ++n) {
            float4 hv = *(const float4*)&hs[n * 128 + c4 * 4];
            acc[n] += w.x * hv.x + w.y * hv.y + w.z * hv.z + w.w * hv.w;
        }
    }
    const float bb = linb[tid] + qpb[tid];
    const float qw0 = qpW[tid * 4 + 0], qw1 = qpW[tid * 4 + 1];
    const float qw2 = qpW[tid * 4 + 2], qw3 = qpW[tid * 4 + 3];
#pragma unroll
    for (int n = 0; n < 16; ++n) {
        int node = base + n;
        if (node < N) {
            xcomb[(size_t)node * 128 + tid] = acc[n] + bb
                + qw0 * xqs[n * 4 + 0] + qw1 * xqs[n * 4 + 1]
                + qw2 * xqs[n * 4 + 2] + qw3 * xqs[n * 4 + 3];
        }
    }
    const int nl = tid >> 3;
    const int which = tid & 7;
    const int qi = which & 3;
    const float4* Wp4 = (const float4*)(((which < 4) ? aqW : akW) + qi * 128);
    float dot = (which < 4) ? aqb[qi] : akb[qi];
    for (int c4 = 0; c4 < 32; ++c4) {
        float4 w = Wp4[c4];
        float4 hv = *(const float4*)&hs[nl * 128 + c4 * 4];
        dot += w.x * hv.x + w.y * hv.y + w.z * hv.z + w.w * hv.w;
    }
    int node = base + nl;
    if (node < N) {
        float val = tanhf(dot) * PI_HALF;
        if (which < 4) qbuf[(size_t)node * 4 + qi] = val;
        else           kbuf[(size_t)node * 4 + qi] = val;
    }
}

// attention circuit per edge -> score; fused block-sum of exp(score)
__global__ void k_att(const float* __restrict__ qb, const float* __restrict__ kb,
                      const int* __restrict__ ei, const float* __restrict__ P,
                      float* __restrict__ scores, float* __restrict__ sumexp,
                      int E, int EP) {
    __shared__ float red[256];
    int e = blockIdx.x * blockDim.x + threadIdx.x;
    float ex = 0.f;
    if (e < EP) {
        int s_, d_;
        if (e < E) { s_ = ei[e]; d_ = ei[E + e]; } else { s_ = d_ = e - E; }
        float4 q = *(const float4*)&qb[(size_t)s_ * 4];
        float4 k = *(const float4*)&kb[(size_t)d_ * 4];
        float sr[16], si[16];
        init_state(sr, si);
        { float s, c; sincosf(0.5f * q.x, &s, &c); ry_g<8>(sr, si, c, s); }
        { float s, c; sincosf(0.5f * q.y, &s, &c); ry_g<4>(sr, si, c, s); }
        { float s, c; sincosf(0.5f * q.z, &s, &c); ry_g<2>(sr, si, c, s); }
        { float s, c; sincosf(0.5f * q.w, &s, &c); ry_g<1>(sr, si, c, s); }
        had_g<8>(sr, si); had_g<4>(sr, si); had_g<2>(sr, si); had_g<1>(sr, si);
        { float s, c; sincosf(0.5f * k.x, &s, &c); cry_g<8, 4>(sr, si, c, s); }
        { float s, c; sincosf(0.5f * k.y, &s, &c); cry_g<4, 2>(sr, si, c, s); }
        { float s, c; sincosf(0.5f * k.z, &s, &c); cry_g<2, 1>(sr, si, c, s); }
        { float s, c; sincosf(0.5f * k.w, &s, &c); cry_g<1, 8>(sr, si, c, s); }
        rot_g<8>(sr, si, P[0], P[1], P[2]);
        rot_g<4>(sr, si, P[3], P[4], P[5]);
        rot_g<2>(sr, si, P[6], P[7], P[8]);
        rot_g<1>(sr, si, P[9], P[10], P[11]);
        float z[4]; zexp_g(sr, si, z);
        float sc = 0.25f * (z[0] + z[1] + z[2] + z[3]);
        scores[e] = sc;
        ex = expf(sc);
    }
    red[threadIdx.x] = ex;
    __syncthreads();
    for (int s = 128; s > 0; s >>= 1) {
        if ((int)threadIdx.x < s) red[threadIdx.x] += red[threadIdx.x + s];
        __syncthreads();
    }
    if (threadIdx.x == 0) atomicAdd(sumexp, red[0]);
}

// ---------------- dst binning (edge_index is layer-invariant: built once) ----

__global__ void k_hist(const int* __restrict__ ei, int* __restrict__ cnt, int E, int EP) {
    int e = blockIdx.x * blockDim.x + threadIdx.x;
    if (e >= EP) return;
    int d_ = (e < E) ? ei[E + e] : e - E;
    atomicAdd(&cnt[d_], 1);
}

// single-block exclusive scan over cnt[N] -> off, cur
__global__ void k_scan(const int* __restrict__ cnt, int* __restrict__ off,
                       int* __restrict__ cur, int N) {
    __shared__ int tot[1024];
    const int t = threadIdx.x;
    const int chunk = (N + 1023) >> 10;
    const int s0 = t * chunk;
    const int s1 = min(s0 + chunk, N);
    int sum = 0;
    for (int i = s0; i < s1; ++i) sum += cnt[i];
    tot[t] = sum;
    __syncthreads();
    for (int d = 1; d < 1024; d <<= 1) {
        int v = (t >= d) ? tot[t - d] : 0;
        __syncthreads();
        tot[t] += v;
        __syncthreads();
    }
    int run = (t == 0) ? 0 : tot[t - 1];
    for (int i = s0; i < s1; ++i) {
        off[i] = run; cur[i] = run;
        run += cnt[i];
    }
}

__global__ void k_fill(const int* __restrict__ ei, int* __restrict__ cur,
                       int* __restrict__ srcs, int* __restrict__ eids, int E, int EP) {
    int e = blockIdx.x * blockDim.x + threadIdx.x;
    if (e >= EP) return;
    int s_, d_;
    if (e < E) { s_ = ei[e]; d_ = ei[E + e]; } else { s_ = d_ = e - E; }
    int pos = atomicAdd(&cur[d_], 1);
    srcs[pos] = s_;
    eids[pos] = e;
}

// watt[slot] = exp(scores[eids[slot]]) / sumexp
__global__ void k_wexp(const float* __restrict__ scores, const int* __restrict__ eids,
                       const float* __restrict__ sumexp, float* __restrict__ watt, int EP) {
    int t = blockIdx.x * blockDim.x + threadIdx.x;
    if (t >= EP) return;
    watt[t] = expf(scores[eids[t]]) / sumexp[0];
}

// one block per dst: h[dst,:] = relu( sum_slot watt[slot]*xcomb[srcs[slot],:] )
__global__ void k_gather(const float* __restrict__ xcomb, const int* __restrict__ srcs,
                         const float* __restrict__ watt, const int* __restrict__ off,
                         const int* __restrict__ cnt, float* __restrict__ h) {
    __shared__ int sS[128];
    __shared__ float wS[128];
    const int b = blockIdx.x;
    const int tid = threadIdx.x;  // 128
    const int start = off[b];
    const int num = cnt[b];
    float acc = 0.f;
    for (int base = 0; base < num; base += 128) {
        int m = min(128, num - base);
        if (tid < m) {
            sS[tid] = srcs[start + base + tid];
            wS[tid] = watt[start + base + tid];
        }
        __syncthreads();
        for (int i = 0; i < m; ++i)
            acc += wS[i] * xcomb[(size_t)sS[i] * 128 + tid];
        __syncthreads();
    }
    h[(size_t)b * 128 + tid] = fmaxf(acc, 0.f);
}

// M = out_W @ path_out_W  (32x4);  v = out_W @ path_out_b + out_b  (32)
__global__ void k_fusemat(const float* __restrict__ outW, const float* __restrict__ outb,
                          const float* __restrict__ poW, const float* __restrict__ pob,
                          float* __restrict__ M, float* __restrict__ v) {
    int t = threadIdx.x;
    if (t < 128) {
        int o = t >> 2, i = t & 3;
        float acc = 0.f;
        for (int j = 0; j < 128; ++j) acc += outW[o * 128 + j] * poW[j * 4 + i];
        M[t] = acc;
    } else if (t < 160) {
        int o = t - 128;
        float acc = outb[o];
        for (int j = 0; j < 128; ++j) acc += outW[o * 128 + j] * pob[j];
        v[o] = acc;
    }
}

// pq[n,0:4] = tanh(path_in_W @ h[n,:] + b)*pi/2 — coalesced LDS-tiled, 32 nodes/block
#define PQ_STRIDE 132  // +4 pad: breaks 16-way bank conflict on per-node row reads
__global__ void k_pq(const float* __restrict__ h, const float* __restrict__ piW,
                     const float* __restrict__ pib, float* __restrict__ pq, int N) {
    __shared__ float hs[32 * PQ_STRIDE];
    const int base = blockIdx.x * 32;
    const int tid = threadIdx.x;  // 128
    for (int idx = tid; idx < 32 * 128; idx += 128) {
        int n = base + (idx >> 7);
        hs[(idx >> 7) * PQ_STRIDE + (idx & 127)] = (n < N) ? h[(size_t)n * 128 + (idx & 127)] : 0.f;
    }
    __syncthreads();
    const int nl = tid >> 2;   // 0..31
    const int i  = tid & 3;    // output row
    float dot = pib[i];
    const float4* w4 = (const float4*)(piW + i * 128);
    for (int c4 = 0; c4 < 32; ++c4) {
        float4 w = w4[c4];
        float4 hv = *(const float4*)&hs[nl * PQ_STRIDE + c4 * 4];
        dot += w.x * hv.x + w.y * hv.y + w.z * hv.z + w.w * hv.w;
    }
    int node = base + nl;
    if (node < N) pq[(size_t)node * 4 + i] = tanhf(dot) * PI_HALF;
}

// path circuit per node + fused epilogue out = M@z + v, coalesced via LDS staging
__global__ void k_pathc(const float* __restrict__ pq, const float* __restrict__ pp,
                        const float* __restrict__ M, const float* __restrict__ v,
                        float* __restrict__ out, int N) {
    __shared__ float zS[256 * 4];
    __shared__ float MS[128];
    __shared__ float vS[32];
    __shared__ float ppS[36];
    const int tid = threadIdx.x;  // 256
    if (tid < 128) MS[tid] = M[tid];
    else if (tid < 160) vS[tid - 128] = v[tid - 128];
    else if (tid < 196) ppS[tid - 160] = pp[tid - 160];
    __syncthreads();
    const int base = blockIdx.x * 256;
    const int n = base + tid;
    if (n < N) {
        float4 a = *(const float4*)&pq[(size_t)n * 4];
        float sr[16], si[16];
        init_state(sr, si);
        had_g<8>(sr, si); had_g<4>(sr, si); had_g<2>(sr, si); had_g<1>(sr, si);
        { float s, c; sincosf(0.5f * a.x, &s, &c); ry_g<8>(sr, si, c, s); }
        { float s, c; sincosf(0.5f * a.y, &s, &c); ry_g<4>(sr, si, c, s); }
        { float s, c; sincosf(0.5f * a.z, &s, &c); ry_g<2>(sr, si, c, s); }
        { float s, c; sincosf(0.5f * a.w, &s, &c); ry_g<1>(sr, si, c, s); }
#pragma unroll
        for (int l = 0; l < 3; ++l) {
            const float* P = ppS + l * 12;
            rot_g<8>(sr, si, P[0], P[1], P[2]);
            rot_g<4>(sr, si, P[3], P[4], P[5]);
            rot_g<2>(sr, si, P[6], P[7], P[8]);
            rot_g<1>(sr, si, P[9], P[10], P[11]);
            cnot_g<8, 4>(sr, si); cnot_g<4, 2>(sr, si); cnot_g<2, 1>(sr, si);
        }
        float z[4]; zexp_g(sr, si, z);
        zS[tid * 4 + 0] = z[0]; zS[tid * 4 + 1] = z[1];
        zS[tid * 4 + 2] = z[2]; zS[tid * 4 + 3] = z[3];
    }
    __syncthreads();
    // cooperative coalesced store of the 256x32 output tile
#pragma unroll
    for (int k = 0; k < 32; ++k) {
        int flat = k * 256 + tid;
        int nl = flat >> 5;
        int o = flat & 31;
        int node = base + nl;
        if (node < N) {
            out[(size_t)node * 32 + o] = vS[o]
                + MS[o * 4 + 0] * zS[nl * 4 + 0] + MS[o * 4 + 1] * zS[nl * 4 + 1]
                + MS[o * 4 + 2] * zS[nl * 4 + 2] + MS[o * 4 + 3] * zS[nl * 4 + 3];
        }
    }
}

// ---------------- launch ----------------------------------------------------

extern "C" void kernel_launch(void* const* d_in, const int* in_sizes, int n_in,
                              void* d_out, int out_size, void* d_ws, size_t ws_size,
                              hipStream_t stream) {
    const float* x     = (const float*)d_in[0];
    const float* W_in  = (const float*)d_in[1];
    const float* b_in  = (const float*)d_in[2];
    const float* linW  = (const float*)d_in[3];
    const float* linb  = (const float*)d_in[4];
    const float* qpW   = (const float*)d_in[5];
    const float* qpb   = (const float*)d_in[6];
    const float* entp  = (const float*)d_in[7];
    const float* aqW   = (const float*)d_in[8];
    const float* aqb   = (const float*)d_in[9];
    const float* akW   = (const float*)d_in[10];
    const float* akb   = (const float*)d_in[11];
    const float* attqp = (const float*)d_in[12];
    const float* pparm = (const float*)d_in[13];
    const float* piW   = (const float*)d_in[14];
    const float* pib   = (const float*)d_in[15];
    const float* poW   = (const float*)d_in[16];
    const float* pob   = (const float*)d_in[17];
    const float* outW  = (const float*)d_in[18];
    const float* outb  = (const float*)d_in[19];
    const int*   ei    = (const int*)d_in[20];

    const int N  = in_sizes[0] / 64;   // 20000
    const int E  = in_sizes[20] / 2;   // 300000
    const int EP = E + N;              // self-loops appended

    float* ws     = (float*)d_ws;
    float* h      = ws;
    float* xcomb  = h      + (size_t)N * 128;
    float* xq     = xcomb  + (size_t)N * 128;
    float* qbuf   = xq     + (size_t)N * 4;
    float* kbuf   = qbuf   + (size_t)N * 4;
    float* pq     = kbuf   + (size_t)N * 4;
    float* scores = pq     + (size_t)N * 4;
    float* watt   = scores + EP;
    float* sumexp = watt   + EP;
    float* Mm     = sumexp + 4;          // keep 16B alignment slack
    float* vv     = Mm + 128;
    int*   cnt    = (int*)(vv + 32);
    int*   off    = cnt + N;
    int*   cur    = off + N;
    int*   srcs   = cur + N;
    int*   eids   = srcs + EP;

    const int nb16 = (N + 15) / 16;
    const int ebl  = (EP + 255) / 256;

    // ---- binning of dst (edge_index identical for both layers) ----
    hipMemsetAsync(cnt, 0, (size_t)N * sizeof(int), stream);
    k_hist<<<ebl, 256, 0, stream>>>(ei, cnt, E, EP);
    k_scan<<<1, 1024, 0, stream>>>(cnt, off, cur, N);
    k_fill<<<ebl, 256, 0, stream>>>(ei, cur, srcs, eids, E, EP);

    k_in<<<nb16, 128, 0, stream>>>(x, W_in, b_in, h, N);

    for (int l = 0; l < 2; ++l) {
        k_ent<<<(N + 255) / 256, 256, 0, stream>>>(h, entp + l * 24, xq, N);
        k_lin<<<nb16, 128, 0, stream>>>(h, xq,
            linW + (size_t)l * 128 * 128, linb + l * 128,
            qpW + (size_t)l * 128 * 4, qpb + l * 128,
            aqW + (size_t)l * 4 * 128, aqb + l * 4,
            akW + (size_t)l * 4 * 128, akb + l * 4,
            xcomb, qbuf, kbuf, N);
        hipMemsetAsync(sumexp, 0, sizeof(float), stream);
        k_att<<<ebl, 256, 0, stream>>>(qbuf, kbuf, ei, attqp + l * 12,
                                       scores, sumexp, E, EP);
        k_wexp<<<ebl, 256, 0, stream>>>(scores, eids, sumexp, watt, EP);
        k_gather<<<N, 128, 0, stream>>>(xcomb, srcs, watt, off, cnt, h);
    }

    k_fusemat<<<1, 192, 0, stream>>>(outW, outb, poW, pob, Mm, vv);
    k_pq<<<(N + 31) / 32, 128, 0, stream>>>(h, piW, pib, pq, N);
    k_pathc<<<(N + 255) / 256, 256, 0, stream>>>(pq, pparm, Mm, vv, (float*)d_out, N);
}

// Round 3
// 396.976 us; speedup vs baseline: 1.5932x; 1.0707x over previous
//
#include <hip/hip_runtime.h>
#include <math.h>

#define PI_HALF 1.57079632679489662f

__device__ __forceinline__ float fast_tanh(float x) {
    float e = __expf(2.f * x);
    return 1.f - 2.f * __builtin_amdgcn_rcpf(e + 1.f);
}

// ---------------- 4-qubit state helpers (compile-time masks -> registers) ----
// wire w (0..3) maps to amplitude-index bit (3-w), i.e. mask = 8 >> w.

__device__ __forceinline__ void init_state(float sr[16], float si[16]) {
#pragma unroll
    for (int i = 0; i < 16; ++i) { sr[i] = 0.f; si[i] = 0.f; }
    sr[0] = 1.f;
}

template<int M>
__device__ __forceinline__ void ry_g(float sr[16], float si[16], float c, float s) {
#pragma unroll
    for (int i = 0; i < 16; ++i) {
        if (i & M) continue;
        const int j = i | M;
        float ar = sr[i], ai = si[i], br = sr[j], bi = si[j];
        sr[i] = c * ar - s * br;  si[i] = c * ai - s * bi;
        sr[j] = s * ar + c * br;  si[j] = s * ai + c * bi;
    }
}

template<int M>
__device__ __forceinline__ void had_g(float sr[16], float si[16]) {
    const float r = 0.70710678118654752f;
#pragma unroll
    for (int i = 0; i < 16; ++i) {
        if (i & M) continue;
        const int j = i | M;
        float ar = sr[i], ai = si[i], br = sr[j], bi = si[j];
        sr[i] = (ar + br) * r;  si[i] = (ai + bi) * r;
        sr[j] = (ar - br) * r;  si[j] = (ai - bi) * r;
    }
}

template<int MC, int MT>
__device__ __forceinline__ void cnot_g(float sr[16], float si[16]) {
#pragma unroll
    for (int i = 0; i < 16; ++i) {
        if (!(i & MC) || (i & MT)) continue;
        const int j = i | MT;
        float tr = sr[i], ti = si[i];
        sr[i] = sr[j]; si[i] = si[j];
        sr[j] = tr;    si[j] = ti;
    }
}

template<int MC, int MT>
__device__ __forceinline__ void cry_g(float sr[16], float si[16], float c, float s) {
#pragma unroll
    for (int i = 0; i < 16; ++i) {
        if (!(i & MC) || (i & MT)) continue;
        const int j = i | MT;
        float ar = sr[i], ai = si[i], br = sr[j], bi = si[j];
        sr[i] = c * ar - s * br;  si[i] = c * ai - s * bi;
        sr[j] = s * ar + c * br;  si[j] = s * ai + c * bi;
    }
}

// Rot gate from a precomputed 8-float matrix {u00r,u00i,u01r,u01i,u10r,u10i,u11r,u11i}
template<int M>
__device__ __forceinline__ void rot_pre(float sr[16], float si[16], const float* __restrict__ u) {
    const float u00r = u[0], u00i = u[1], u01r = u[2], u01i = u[3];
    const float u10r = u[4], u10i = u[5], u11r = u[6], u11i = u[7];
#pragma unroll
    for (int i = 0; i < 16; ++i) {
        if (i & M) continue;
        const int j = i | M;
        float ar = sr[i], ai = si[i], br = sr[j], bi = si[j];
        sr[i] = u00r * ar - u00i * ai + u01r * br - u01i * bi;
        si[i] = u00r * ai + u00i * ar + u01r * bi + u01i * br;
        sr[j] = u10r * ar - u10i * ai + u11r * br - u11i * bi;
        si[j] = u10r * ai + u10i * ar + u11r * bi + u11i * br;
    }
}

__device__ __forceinline__ void zexp_g(const float sr[16], const float si[16], float z[4]) {
    float p[16];
#pragma unroll
    for (int i = 0; i < 16; ++i) p[i] = sr[i] * sr[i] + si[i] * si[i];
    z[0] = z[1] = z[2] = z[3] = 0.f;
#pragma unroll
    for (int i = 0; i < 16; ++i) {
        z[0] += (i & 8) ? -p[i] : p[i];
        z[1] += (i & 4) ? -p[i] : p[i];
        z[2] += (i & 2) ? -p[i] : p[i];
        z[3] += (i & 1) ? -p[i] : p[i];
    }
}

// ---------------- setup: precompute rot matrices + fused output matrix -------
// rotbuf layout (8 floats per matrix):
//   [0..15]  ent: [l][sub][wire] (2*2*4)
//   [16..23] att: [l][wire]      (2*4)
//   [24..35] path: [l][wire]     (3*4)
__global__ void k_setup(const float* __restrict__ entp, const float* __restrict__ attqp,
                        const float* __restrict__ pparm,
                        const float* __restrict__ outW, const float* __restrict__ outb,
                        const float* __restrict__ poW, const float* __restrict__ pob,
                        float* __restrict__ rotbuf, float* __restrict__ M,
                        float* __restrict__ v) {
    const int t = threadIdx.x;
    if (t < 36) {
        const float* p;
        if (t < 16)      p = entp  + t * 3;
        else if (t < 24) p = attqp + (t - 16) * 3;
        else             p = pparm + (t - 24) * 3;
        float phi = p[0], theta = p[1], omega = p[2];
        float st, ct; sincosf(0.5f * theta, &st, &ct);
        float sp, cp; sincosf(0.5f * (phi + omega), &sp, &cp);
        float sm, cm; sincosf(0.5f * (phi - omega), &sm, &cm);
        float* u = rotbuf + t * 8;
        u[0] =  ct * cp;  u[1] = -ct * sp;
        u[2] = -st * cm;  u[3] = -st * sm;
        u[4] =  st * cm;  u[5] = -st * sm;
        u[6] =  ct * cp;  u[7] =  ct * sp;
    } else if (t >= 64 && t < 192) {
        int t2 = t - 64;
        int o = t2 >> 2, i = t2 & 3;
        float acc = 0.f;
        for (int j = 0; j < 128; ++j) acc += outW[o * 128 + j] * poW[j * 4 + i];
        M[t2] = acc;
    } else if (t >= 192 && t < 224) {
        int o = t - 192;
        float acc = outb[o];
        for (int j = 0; j < 128; ++j) acc += outW[o * 128 + j] * pob[j];
        v[o] = acc;
    }
}

// ---------------- kernels ---------------------------------------------------

// h = relu(x @ W_in^T + b_in), x:[N,64] W:[128,64] -> h:[N,128]
__global__ void k_in(const float* __restrict__ x, const float* __restrict__ W,
                     const float* __restrict__ b, float* __restrict__ h, int N) {
    __shared__ float xs[16 * 64];
    const int base = blockIdx.x * 16;
    const int tid = threadIdx.x;  // 128
    for (int idx = tid; idx < 16 * 64; idx += 128) {
        int n = base + (idx >> 6);
        xs[idx] = (n < N) ? x[(size_t)n * 64 + (idx & 63)] : 0.f;
    }
    __syncthreads();
    float acc[16];
#pragma unroll
    for (int n = 0; n < 16; ++n) acc[n] = 0.f;
    const float4* wr4 = (const float4*)(W + tid * 64);
    for (int c4 = 0; c4 < 16; ++c4) {
        float4 w = wr4[c4];
#pragma unroll
        for (int n = 0; n < 16; ++n) {
            float4 hv = *(const float4*)&xs[n * 64 + c4 * 4];
            acc[n] += w.x * hv.x + w.y * hv.y + w.z * hv.z + w.w * hv.w;
        }
    }
    const float bb = b[tid];
#pragma unroll
    for (int n = 0; n < 16; ++n) {
        int node = base + n;
        if (node < N) h[(size_t)node * 128 + tid] = fmaxf(acc[n] + bb, 0.f);
    }
}

// entangle circuit per node; rotE = 8 precomputed matrices (2 sublayers x 4 wires)
__global__ void k_ent(const float* __restrict__ h, const float* __restrict__ rotE,
                      float* __restrict__ xq, int N) {
    int n = blockIdx.x * blockDim.x + threadIdx.x;
    if (n >= N) return;
    float4 hv = *(const float4*)&h[(size_t)n * 128];
    float sr[16], si[16];
    init_state(sr, si);
    { float s, c; __sincosf(fast_tanh(hv.x) * (0.5f * PI_HALF), &s, &c); ry_g<8>(sr, si, c, s); }
    { float s, c; __sincosf(fast_tanh(hv.y) * (0.5f * PI_HALF), &s, &c); ry_g<4>(sr, si, c, s); }
    { float s, c; __sincosf(fast_tanh(hv.z) * (0.5f * PI_HALF), &s, &c); ry_g<2>(sr, si, c, s); }
    { float s, c; __sincosf(fast_tanh(hv.w) * (0.5f * PI_HALF), &s, &c); ry_g<1>(sr, si, c, s); }
#pragma unroll
    for (int l = 0; l < 2; ++l) {
        cnot_g<8, 4>(sr, si); cnot_g<4, 2>(sr, si); cnot_g<2, 1>(sr, si);
        const float* P = rotE + l * 32;
        rot_pre<8>(sr, si, P);
        rot_pre<4>(sr, si, P + 8);
        rot_pre<2>(sr, si, P + 16);
        rot_pre<1>(sr, si, P + 24);
        cnot_g<8, 1>(sr, si);  // CNOT(0, 3)
    }
    float z[4]; zexp_g(sr, si, z);
    *(float4*)&xq[(size_t)n * 4] = make_float4(z[0], z[1], z[2], z[3]);
}

// per-node: x_comb; q/k half-angle (cos,sin) pairs -> qbuf/kbuf [N][8]
__global__ void k_lin(const float* __restrict__ h, const float* __restrict__ xq,
                      const float* __restrict__ linW, const float* __restrict__ linb,
                      const float* __restrict__ qpW, const float* __restrict__ qpb,
                      const float* __restrict__ aqW, const float* __restrict__ aqb,
                      const float* __restrict__ akW, const float* __restrict__ akb,
                      float* __restrict__ xcomb, float* __restrict__ qbuf,
                      float* __restrict__ kbuf, int N) {
    __shared__ float hs[16 * 128];
    __shared__ float xqs[16 * 4];
    const int base = blockIdx.x * 16;
    const int tid = threadIdx.x;  // 128
    for (int idx = tid; idx < 16 * 128; idx += 128) {
        int n = base + (idx >> 7);
        hs[idx] = (n < N) ? h[(size_t)n * 128 + (idx & 127)] : 0.f;
    }
    if (tid < 64) {
        int n = base + (tid >> 2);
        xqs[tid] = (n < N) ? xq[(size_t)n * 4 + (tid & 3)] : 0.f;
    }
    __syncthreads();
    float acc[16];
#pragma unroll
    for (int n = 0; n < 16; ++n) acc[n] = 0.f;
    const float4* wr4 = (const float4*)(linW + tid * 128);
    for (int c4 = 0; c4 < 32; ++c4) {
        float4 w = wr4[c4];
#pragma unroll
        for (int n = 0; n < 16; ++n) {
            float4 hv = *(const float4*)&hs[n * 128 + c4 * 4];
            acc[n] += w.x * hv.x + w.y * hv.y + w.z * hv.z + w.w * hv.w;
        }
    }
    const float bb = linb[tid] + qpb[tid];
    const float qw0 = qpW[tid * 4 + 0], qw1 = qpW[tid * 4 + 1];
    const float qw2 = qpW[tid * 4 + 2], qw3 = qpW[tid * 4 + 3];
#pragma unroll
    for (int n = 0; n < 16; ++n) {
        int node = base + n;
        if (node < N) {
            xcomb[(size_t)node * 128 + tid] = acc[n] + bb
                + qw0 * xqs[n * 4 + 0] + qw1 * xqs[n * 4 + 1]
                + qw2 * xqs[n * 4 + 2] + qw3 * xqs[n * 4 + 3];
        }
    }
    const int nl = tid >> 3;
    const int which = tid & 7;
    const int qi = which & 3;
    const float4* Wp4 = (const float4*)(((which < 4) ? aqW : akW) + qi * 128);
    float dot = (which < 4) ? aqb[qi] : akb[qi];
    for (int c4 = 0; c4 < 32; ++c4) {
        float4 w = Wp4[c4];
        float4 hv = *(const float4*)&hs[nl * 128 + c4 * 4];
        dot += w.x * hv.x + w.y * hv.y + w.z * hv.z + w.w * hv.w;
    }
    int node = base + nl;
    if (node < N) {
        float half = fast_tanh(dot) * (0.5f * PI_HALF);
        float s, c; __sincosf(half, &s, &c);
        float* dst = ((which < 4) ? qbuf : kbuf) + (size_t)node * 8 + qi * 2;
        dst[0] = c; dst[1] = s;
    }
}

// attention circuit per edge -> exp(score) written slot-ordered; block-sum to sumexp
__global__ void k_att(const float* __restrict__ qb, const float* __restrict__ kb,
                      const int* __restrict__ ei, const float* __restrict__ RA,
                      const int* __restrict__ inv, float* __restrict__ escore,
                      float* __restrict__ sumexp, int E, int EP) {
    __shared__ float red[256];
    int e = blockIdx.x * blockDim.x + threadIdx.x;
    float ex = 0.f;
    if (e < EP) {
        int s_, d_;
        if (e < E) { s_ = ei[e]; d_ = ei[E + e]; } else { s_ = d_ = e - E; }
        float4 qa = *(const float4*)&qb[(size_t)s_ * 8];
        float4 qc = *(const float4*)&qb[(size_t)s_ * 8 + 4];
        float4 ka = *(const float4*)&kb[(size_t)d_ * 8];
        float4 kc = *(const float4*)&kb[(size_t)d_ * 8 + 4];
        float sr[16], si[16];
        init_state(sr, si);
        ry_g<8>(sr, si, qa.x, qa.y);
        ry_g<4>(sr, si, qa.z, qa.w);
        ry_g<2>(sr, si, qc.x, qc.y);
        ry_g<1>(sr, si, qc.z, qc.w);
        had_g<8>(sr, si); had_g<4>(sr, si); had_g<2>(sr, si); had_g<1>(sr, si);
        cry_g<8, 4>(sr, si, ka.x, ka.y);
        cry_g<4, 2>(sr, si, ka.z, ka.w);
        cry_g<2, 1>(sr, si, kc.x, kc.y);
        cry_g<1, 8>(sr, si, kc.z, kc.w);
        rot_pre<8>(sr, si, RA);
        rot_pre<4>(sr, si, RA + 8);
        rot_pre<2>(sr, si, RA + 16);
        rot_pre<1>(sr, si, RA + 24);
        float z[4]; zexp_g(sr, si, z);
        float sc = 0.25f * (z[0] + z[1] + z[2] + z[3]);
        ex = __expf(sc);
        escore[inv[e]] = ex;
    }
    red[threadIdx.x] = ex;
    __syncthreads();
    for (int s = 128; s > 0; s >>= 1) {
        if ((int)threadIdx.x < s) red[threadIdx.x] += red[threadIdx.x + s];
        __syncthreads();
    }
    if (threadIdx.x == 0) atomicAdd(sumexp, red[0]);
}

// ---------------- dst binning (edge_index is layer-invariant: built once) ----

__global__ void k_hist(const int* __restrict__ ei, int* __restrict__ cnt, int E, int EP) {
    int e = blockIdx.x * blockDim.x + threadIdx.x;
    if (e >= EP) return;
    int d_ = (e < E) ? ei[E + e] : e - E;
    atomicAdd(&cnt[d_], 1);
}

__global__ void k_scan(const int* __restrict__ cnt, int* __restrict__ off,
                       int* __restrict__ cur, int N) {
    __shared__ int tot[1024];
    const int t = threadIdx.x;
    const int chunk = (N + 1023) >> 10;
    const int s0 = t * chunk;
    const int s1 = min(s0 + chunk, N);
    int sum = 0;
    for (int i = s0; i < s1; ++i) sum += cnt[i];
    tot[t] = sum;
    __syncthreads();
    for (int d = 1; d < 1024; d <<= 1) {
        int v = (t >= d) ? tot[t - d] : 0;
        __syncthreads();
        tot[t] += v;
        __syncthreads();
    }
    int run = (t == 0) ? 0 : tot[t - 1];
    for (int i = s0; i < s1; ++i) {
        off[i] = run; cur[i] = run;
        run += cnt[i];
    }
}

__global__ void k_fill(const int* __restrict__ ei, int* __restrict__ cur,
                       int* __restrict__ srcs, int* __restrict__ inv, int E, int EP) {
    int e = blockIdx.x * blockDim.x + threadIdx.x;
    if (e >= EP) return;
    int s_, d_;
    if (e < E) { s_ = ei[e]; d_ = ei[E + e]; } else { s_ = d_ = e - E; }
    int pos = atomicAdd(&cur[d_], 1);
    srcs[pos] = s_;
    inv[e] = pos;
}

// one block per dst: h[dst,:] = relu( invS * sum_slot escore[slot]*xcomb[srcs[slot],:] )
__global__ void k_gather(const float* __restrict__ xcomb, const int* __restrict__ srcs,
                         const float* __restrict__ escore, const int* __restrict__ off,
                         const int* __restrict__ cnt, const float* __restrict__ sumexp,
                         float* __restrict__ h) {
    __shared__ int sS[128];
    __shared__ float wS[128];
    const int b = blockIdx.x;
    const int tid = threadIdx.x;  // 128
    const int start = off[b];
    const int num = cnt[b];
    float acc = 0.f;
    for (int base = 0; base < num; base += 128) {
        int m = min(128, num - base);
        if (tid < m) {
            sS[tid] = srcs[start + base + tid];
            wS[tid] = escore[start + base + tid];
        }
        __syncthreads();
        for (int i = 0; i < m; ++i)
            acc += wS[i] * xcomb[(size_t)sS[i] * 128 + tid];
        __syncthreads();
    }
    const float invS = __builtin_amdgcn_rcpf(sumexp[0]);
    h[(size_t)b * 128 + tid] = fmaxf(acc * invS, 0.f);
}

// pq half-angle (c,s) pairs: pq8[n][8] — coalesced LDS-tiled, 32 nodes/block
#define PQ_STRIDE 132
__global__ void k_pq(const float* __restrict__ h, const float* __restrict__ piW,
                     const float* __restrict__ pib, float* __restrict__ pq8, int N) {
    __shared__ float hs[32 * PQ_STRIDE];
    const int base = blockIdx.x * 32;
    const int tid = threadIdx.x;  // 128
    for (int idx = tid; idx < 32 * 128; idx += 128) {
        int n = base + (idx >> 7);
        hs[(idx >> 7) * PQ_STRIDE + (idx & 127)] = (n < N) ? h[(size_t)n * 128 + (idx & 127)] : 0.f;
    }
    __syncthreads();
    const int nl = tid >> 2;
    const int i  = tid & 3;
    float dot = pib[i];
    const float4* w4 = (const float4*)(piW + i * 128);
    for (int c4 = 0; c4 < 32; ++c4) {
        float4 w = w4[c4];
        float4 hv = *(const float4*)&hs[nl * PQ_STRIDE + c4 * 4];
        dot += w.x * hv.x + w.y * hv.y + w.z * hv.z + w.w * hv.w;
    }
    int node = base + nl;
    if (node < N) {
        float half = fast_tanh(dot) * (0.5f * PI_HALF);
        float s, c; __sincosf(half, &s, &c);
        pq8[(size_t)node * 8 + i * 2]     = c;
        pq8[(size_t)node * 8 + i * 2 + 1] = s;
    }
}

// path circuit per node + fused epilogue out = M@z + v, coalesced via LDS staging
__global__ void k_pathc(const float* __restrict__ pq8, const float* __restrict__ RP,
                        const float* __restrict__ M, const float* __restrict__ v,
                        float* __restrict__ out, int N) {
    __shared__ float zS[256 * 4];
    __shared__ float MS[128];
    __shared__ float vS[32];
    const int tid = threadIdx.x;  // 256
    if (tid < 128) MS[tid] = M[tid];
    else if (tid < 160) vS[tid - 128] = v[tid - 128];
    __syncthreads();
    const int base = blockIdx.x * 256;
    const int n = base + tid;
    if (n < N) {
        float4 pa = *(const float4*)&pq8[(size_t)n * 8];
        float4 pc = *(const float4*)&pq8[(size_t)n * 8 + 4];
        float sr[16], si[16];
        init_state(sr, si);
        had_g<8>(sr, si); had_g<4>(sr, si); had_g<2>(sr, si); had_g<1>(sr, si);
        ry_g<8>(sr, si, pa.x, pa.y);
        ry_g<4>(sr, si, pa.z, pa.w);
        ry_g<2>(sr, si, pc.x, pc.y);
        ry_g<1>(sr, si, pc.z, pc.w);
#pragma unroll
        for (int l = 0; l < 3; ++l) {
            const float* P = RP + l * 32;
            rot_pre<8>(sr, si, P);
            rot_pre<4>(sr, si, P + 8);
            rot_pre<2>(sr, si, P + 16);
            rot_pre<1>(sr, si, P + 24);
            cnot_g<8, 4>(sr, si); cnot_g<4, 2>(sr, si); cnot_g<2, 1>(sr, si);
        }
        float z[4]; zexp_g(sr, si, z);
        zS[tid * 4 + 0] = z[0]; zS[tid * 4 + 1] = z[1];
        zS[tid * 4 + 2] = z[2]; zS[tid * 4 + 3] = z[3];
    }
    __syncthreads();
#pragma unroll
    for (int k = 0; k < 32; ++k) {
        int flat = k * 256 + tid;
        int nl = flat >> 5;
        int o = flat & 31;
        int node = base + nl;
        if (node < N) {
            out[(size_t)node * 32 + o] = vS[o]
                + MS[o * 4 + 0] * zS[nl * 4 + 0] + MS[o * 4 + 1] * zS[nl * 4 + 1]
                + MS[o * 4 + 2] * zS[nl * 4 + 2] + MS[o * 4 + 3] * zS[nl * 4 + 3];
        }
    }
}

// ---------------- launch ----------------------------------------------------

extern "C" void kernel_launch(void* const* d_in, const int* in_sizes, int n_in,
                              void* d_out, int out_size, void* d_ws, size_t ws_size,
                              hipStream_t stream) {
    const float* x     = (const float*)d_in[0];
    const float* W_in  = (const float*)d_in[1];
    const float* b_in  = (const float*)d_in[2];
    const float* linW  = (const float*)d_in[3];
    const float* linb  = (const float*)d_in[4];
    const float* qpW   = (const float*)d_in[5];
    const float* qpb   = (const float*)d_in[6];
    const float* entp  = (const float*)d_in[7];
    const float* aqW   = (const float*)d_in[8];
    const float* aqb   = (const float*)d_in[9];
    const float* akW   = (const float*)d_in[10];
    const float* akb   = (const float*)d_in[11];
    const float* attqp = (const float*)d_in[12];
    const float* pparm = (const float*)d_in[13];
    const float* piW   = (const float*)d_in[14];
    const float* pib   = (const float*)d_in[15];
    const float* poW   = (const float*)d_in[16];
    const float* pob   = (const float*)d_in[17];
    const float* outW  = (const float*)d_in[18];
    const float* outb  = (const float*)d_in[19];
    const int*   ei    = (const int*)d_in[20];

    const int N  = in_sizes[0] / 64;   // 20000
    const int E  = in_sizes[20] / 2;   // 300000
    const int EP = E + N;              // self-loops appended

    float* ws     = (float*)d_ws;
    float* h      = ws;
    float* xcomb  = h      + (size_t)N * 128;
    float* xq     = xcomb  + (size_t)N * 128;
    float* qbuf   = xq     + (size_t)N * 4;
    float* kbuf   = qbuf   + (size_t)N * 8;
    float* pq8    = kbuf   + (size_t)N * 8;
    float* escore = pq8    + (size_t)N * 8;
    float* rotbuf = escore + EP;
    float* Mm     = rotbuf + 36 * 8;
    float* vv     = Mm + 128;
    int*   cnt    = (int*)(vv + 32);
    float* sumexp = (float*)(cnt + N);   // 2 slots (one per layer), zeroed with cnt
    int*   off    = (int*)(sumexp + 4);
    int*   cur    = off + N;
    int*   srcs   = cur + N;
    int*   inv    = srcs + EP;

    const float* rotE = rotbuf;          // 16 matrices
    const float* rotA = rotbuf + 128;    // 8 matrices
    const float* rotP = rotbuf + 192;    // 12 matrices

    const int nb16 = (N + 15) / 16;
    const int ebl  = (EP + 255) / 256;

    hipMemsetAsync(cnt, 0, (size_t)(N + 4) * sizeof(int), stream);
    k_hist<<<ebl, 256, 0, stream>>>(ei, cnt, E, EP);
    k_scan<<<1, 1024, 0, stream>>>(cnt, off, cur, N);
    k_fill<<<ebl, 256, 0, stream>>>(ei, cur, srcs, inv, E, EP);
    k_setup<<<1, 256, 0, stream>>>(entp, attqp, pparm, outW, outb, poW, pob,
                                   rotbuf, Mm, vv);
    k_in<<<nb16, 128, 0, stream>>>(x, W_in, b_in, h, N);

    for (int l = 0; l < 2; ++l) {
        k_ent<<<(N + 255) / 256, 256, 0, stream>>>(h, rotE + l * 64, xq, N);
        k_lin<<<nb16, 128, 0, stream>>>(h, xq,
            linW + (size_t)l * 128 * 128, linb + l * 128,
            qpW + (size_t)l * 128 * 4, qpb + l * 128,
            aqW + (size_t)l * 4 * 128, aqb + l * 4,
            akW + (size_t)l * 4 * 128, akb + l * 4,
            xcomb, qbuf, kbuf, N);
        k_att<<<ebl, 256, 0, stream>>>(qbuf, kbuf, ei, rotA + l * 32, inv,
                                       escore, sumexp + l, E, EP);
        k_gather<<<N, 128, 0, stream>>>(xcomb, srcs, escore, off, cnt, sumexp + l, h);
    }

    k_pq<<<(N + 31) / 32, 128, 0, stream>>>(h, piW, pib, pq8, N);
    k_pathc<<<(N + 255) / 256, 256, 0, stream>>>(pq8, rotP, Mm, vv, (float*)d_out, N);
}